// Round 4
// baseline (885.970 us; speedup 1.0000x reference)
//
#include <hip/hip_runtime.h>
#include <hip/hip_bf16.h>

typedef unsigned short u16;

#define NN   100000
#define NE   1600000
#define DIN  512
#define DHID 128
#define DOUT 40
#define NB   98          // ceil(NN / 1024) scan blocks

__device__ __forceinline__ float bf2f(u16 u) {
  union { unsigned int i; float f; } v; v.i = ((unsigned int)u) << 16; return v.f;
}
__device__ __forceinline__ u16 f2bf(float f) {
  __hip_bfloat16 h = __float2bfloat16(f);
  return *reinterpret_cast<u16*>(&h);
}

// ---------------- graph build ----------------
// dtypes (HW-verified over rounds 1-3): ei int32, x/W1/b1/W2/b2 fp32, d_out fp32.

__global__ __launch_bounds__(256) void k_count(const int* __restrict__ ei, int* __restrict__ cnt) {
  int e = blockIdx.x * 256 + threadIdx.x;      // grid sized exactly NE/256
  int d = ei[NE + e];
  atomicAdd(&cnt[d], 1);
}

__global__ __launch_bounds__(256) void k_dinv(const int* __restrict__ cnt, float* __restrict__ dinv) {
  int i = blockIdx.x * 256 + threadIdx.x;
  if (i < NN) dinv[i] = rsqrtf((float)(cnt[i] + 1));   // +1 self-loop, always > 0
}

__global__ __launch_bounds__(256) void k_blocksum(const int* __restrict__ cnt, int* __restrict__ bsum) {
  __shared__ int s[256];
  int b = blockIdx.x, t = threadIdx.x;
  int base = b * 1024 + t * 4;
  int tot = 0;
  if (base < NN) { int4 v = *(const int4*)&cnt[base]; tot = v.x + v.y + v.z + v.w; }
  s[t] = tot; __syncthreads();
  for (int o = 128; o > 0; o >>= 1) { if (t < o) s[t] += s[t + o]; __syncthreads(); }
  if (t == 0) bsum[b] = s[0];
}

__global__ __launch_bounds__(128) void k_scanbsum(int* __restrict__ bsum) {
  __shared__ int s[128];
  int t = threadIdx.x;
  int v = (t < NB) ? bsum[t] : 0;
  s[t] = v; __syncthreads();
  for (int o = 1; o < 128; o <<= 1) {
    int add = (t >= o) ? s[t - o] : 0;
    __syncthreads();
    s[t] += add;
    __syncthreads();
  }
  if (t < NB) bsum[t] = s[t] - v;   // exclusive scan of block totals
}

__global__ __launch_bounds__(256) void k_scan3(const int* __restrict__ cnt, const int* __restrict__ bsum,
                                               int* __restrict__ offs) {
  __shared__ int s[256];
  int b = blockIdx.x, t = threadIdx.x;
  int base = b * 1024 + t * 4;
  int4 v = make_int4(0, 0, 0, 0);
  if (base < NN) v = *(const int4*)&cnt[base];
  int tot = v.x + v.y + v.z + v.w;
  s[t] = tot; __syncthreads();
  for (int o = 1; o < 256; o <<= 1) {
    int add = (t >= o) ? s[t - o] : 0;
    __syncthreads();
    s[t] += add;
    __syncthreads();
  }
  int tp = s[t] - tot;              // exclusive prefix of thread totals
  int b0 = bsum[b] + tp;
  if (base < NN) {
    int4 o4;
    o4.x = b0;
    o4.y = b0 + v.x;
    o4.z = b0 + v.x + v.y;
    o4.w = b0 + v.x + v.y + v.z;
    *(int4*)&offs[base] = o4;
  }
  if (b == 0 && t == 0) offs[NN] = NE;
}

__global__ __launch_bounds__(256) void k_scatter(const int* __restrict__ ei, const int* __restrict__ offs,
                                                 int* __restrict__ cursor, int* __restrict__ csr) {
  int e = blockIdx.x * 256 + threadIdx.x;
  int srcv = ei[e];
  int d = ei[NE + e];
  int pos = offs[d] + atomicAdd(&cursor[d], 1);
  csr[pos] = srcv;
}

// ---------------- GEMM1: h1[NN][128] = x[NN][512] @ W1[512][128] (fp32 in, bf16 out) --------

__global__ __launch_bounds__(256) void k_gemm1(const float* __restrict__ x, const float* __restrict__ W1,
                                               u16* __restrict__ h1) {
  __shared__ float xs[64][66];      // 64 rows x 64-K chunk, padded           (16.9 KB)
  __shared__ float ws[64][128];     // K-chunk x all 128 cols                 (32 KB)
  int t = threadIdx.x;
  int row0 = blockIdx.x * 64;
  int cg = t & 31, rg = t >> 5;
  int c4 = cg * 4, r8 = rg * 8;
  float acc[8][4];
#pragma unroll
  for (int i = 0; i < 8; i++)
#pragma unroll
    for (int j = 0; j < 4; j++) acc[i][j] = 0.f;

  for (int k0 = 0; k0 < DIN; k0 += 64) {
    // stage x tile: 64 rows x 64 K (float4 per unit)
#pragma unroll
    for (int it = 0; it < 4; it++) {
      int u = t + it * 256;          // 0..1023 float4 units
      int row = u >> 4, seg = u & 15;
      float4 v = make_float4(0.f, 0.f, 0.f, 0.f);
      int gr = row0 + row;
      if (gr < NN) v = *(const float4*)&x[gr * DIN + k0 + seg * 4];
      xs[row][seg * 4 + 0] = v.x;
      xs[row][seg * 4 + 1] = v.y;
      xs[row][seg * 4 + 2] = v.z;
      xs[row][seg * 4 + 3] = v.w;
    }
    // stage W1 chunk: 64 x 128 (contiguous float4)
#pragma unroll
    for (int it = 0; it < 8; it++) {
      int u = t + it * 256;          // 0..2047 float4 units
      int row = u >> 5, seg = u & 31;
      *(float4*)&ws[row][seg * 4] = *(const float4*)&W1[(k0 + row) * DHID + seg * 4];
    }
    __syncthreads();

    for (int k = 0; k < 64; k += 2) {
      float2 xv[8];
#pragma unroll
      for (int i = 0; i < 8; i++) xv[i] = *(const float2*)&xs[r8 + i][k];
      float4 wa = *(const float4*)&ws[k][c4];
      float4 wb = *(const float4*)&ws[k + 1][c4];
#pragma unroll
      for (int i = 0; i < 8; i++) {
        acc[i][0] += xv[i].x * wa.x + xv[i].y * wb.x;
        acc[i][1] += xv[i].x * wa.y + xv[i].y * wb.y;
        acc[i][2] += xv[i].x * wa.z + xv[i].y * wb.z;
        acc[i][3] += xv[i].x * wa.w + xv[i].y * wb.w;
      }
    }
    __syncthreads();
  }
#pragma unroll
  for (int i = 0; i < 8; i++) {
    int gr = row0 + r8 + i;
    if (gr < NN) {
      ushort4 o;
      o.x = f2bf(acc[i][0]); o.y = f2bf(acc[i][1]);
      o.z = f2bf(acc[i][2]); o.w = f2bf(acc[i][3]);
      *(ushort4*)&h1[gr * DHID + c4] = o;
    }
  }
}

// ---------------- prop1: g = relu(b1 + Ahat @ h1), bf16 intermediate ----------------

__global__ __launch_bounds__(128) void k_prop1(const u16* __restrict__ h1, const float* __restrict__ dinv,
                                               const int* __restrict__ offs, const int* __restrict__ csr,
                                               const float* __restrict__ b1, u16* __restrict__ g) {
  int n = blockIdx.x, f = threadIdx.x;
  float dn = dinv[n];
  float acc = b1[f] + dn * dn * bf2f(h1[n * DHID + f]);   // self-loop
  int p = offs[n], p1 = offs[n + 1];
  for (; p + 4 <= p1; p += 4) {
    int s0 = csr[p], s1 = csr[p + 1], s2 = csr[p + 2], s3 = csr[p + 3];
    float w0 = dinv[s0], w1 = dinv[s1], w2 = dinv[s2], w3 = dinv[s3];
    float v0 = bf2f(h1[s0 * DHID + f]);
    float v1 = bf2f(h1[s1 * DHID + f]);
    float v2 = bf2f(h1[s2 * DHID + f]);
    float v3 = bf2f(h1[s3 * DHID + f]);
    acc += dn * (w0 * v0 + w1 * v1 + w2 * v2 + w3 * v3);
  }
  for (; p < p1; p++) {
    int s0 = csr[p];
    acc += dn * dinv[s0] * bf2f(h1[s0 * DHID + f]);
  }
  g[n * DHID + f] = f2bf(fmaxf(acc, 0.f));
}

// ---------------- GEMM2: h2[NN][40] = g[NN][128] @ W2[128][40] ----------------

__global__ __launch_bounds__(320) void k_gemm2(const u16* __restrict__ g, const float* __restrict__ W2,
                                               u16* __restrict__ h2) {
  __shared__ float w2s[DHID][DOUT];   // 20 KB
  __shared__ float gs[8][DHID];       // 4 KB
  int t = threadIdx.x;
  int row0 = blockIdx.x * 8;
  for (int idx = t; idx < DHID * DOUT; idx += 320) ((float*)w2s)[idx] = W2[idx];
  for (int idx = t; idx < 8 * DHID; idx += 320) {
    int r = idx >> 7, k = idx & 127;
    int gr = row0 + r;
    ((float*)gs)[idx] = (gr < NN) ? bf2f(g[gr * DHID + k]) : 0.f;
  }
  __syncthreads();
  int r = t / DOUT, c = t % DOUT;     // 8 rows x 40 cols = 320 threads exactly
  float acc = 0.f;
#pragma unroll
  for (int k = 0; k < DHID; k += 4) {
    float4 gv = *(const float4*)&gs[r][k];
    acc += gv.x * w2s[k][c] + gv.y * w2s[k + 1][c] + gv.z * w2s[k + 2][c] + gv.w * w2s[k + 3][c];
  }
  int gr = row0 + r;
  if (gr < NN) h2[gr * DOUT + c] = f2bf(acc);
}

// ---------------- prop2 + log_softmax, fp32 out ----------------

__global__ __launch_bounds__(64) void k_prop2(const u16* __restrict__ h2, const float* __restrict__ dinv,
                                              const int* __restrict__ offs, const int* __restrict__ csr,
                                              const float* __restrict__ b2, float* __restrict__ out) {
  int n = blockIdx.x, c = threadIdx.x;
  bool act = c < DOUT;
  float dn = dinv[n];
  float acc = act ? (b2[c] + dn * dn * bf2f(h2[n * DOUT + c])) : 0.f;
  int p = offs[n], p1 = offs[n + 1];
  for (; p + 4 <= p1; p += 4) {
    int s0 = csr[p], s1 = csr[p + 1], s2 = csr[p + 2], s3 = csr[p + 3];
    float w0 = dinv[s0], w1 = dinv[s1], w2 = dinv[s2], w3 = dinv[s3];
    float v0 = act ? bf2f(h2[s0 * DOUT + c]) : 0.f;
    float v1 = act ? bf2f(h2[s1 * DOUT + c]) : 0.f;
    float v2 = act ? bf2f(h2[s2 * DOUT + c]) : 0.f;
    float v3 = act ? bf2f(h2[s3 * DOUT + c]) : 0.f;
    acc += dn * (w0 * v0 + w1 * v1 + w2 * v2 + w3 * v3);
  }
  for (; p < p1; p++) {
    int s0 = csr[p];
    float v0 = act ? bf2f(h2[s0 * DOUT + c]) : 0.f;
    acc += dn * dinv[s0] * v0;
  }
  float logit = act ? acc : -INFINITY;
  float mx = logit;
#pragma unroll
  for (int o = 32; o > 0; o >>= 1) mx = fmaxf(mx, __shfl_xor(mx, o));
  float pv = act ? __expf(logit - mx) : 0.f;
  float sm = pv;
#pragma unroll
  for (int o = 32; o > 0; o >>= 1) sm += __shfl_xor(sm, o);
  if (act) out[n * DOUT + c] = logit - mx - logf(sm);
}

// ---------------- launch ----------------

extern "C" void kernel_launch(void* const* d_in, const int* in_sizes, int n_in,
                              void* d_out, int out_size, void* d_ws, size_t ws_size,
                              hipStream_t stream) {
  const float* x  = (const float*)d_in[0];   // fp32
  const int* ei   = (const int*)d_in[1];     // int32 on device
  const float* W1 = (const float*)d_in[2];
  const float* b1 = (const float*)d_in[3];
  const float* W2 = (const float*)d_in[4];
  const float* b2 = (const float*)d_in[5];
  float* out      = (float*)d_out;           // fp32 output

  char* ws = (char*)d_ws;
  // layout (bytes): cnt 400000 | cursor 400000 | dinv 400000 | offs 400128 | bsum 512 | csr 6400000 |
  //                 h1 25600000 (h2 overlays h1 - h1 dead after prop1) | g 25600000 -> total ~59.2 MB
  int*   cnt    = (int*)(ws + 0);
  int*   cursor = (int*)(ws + 400000);
  float* dinv   = (float*)(ws + 800000);
  int*   offs   = (int*)(ws + 1200000);
  int*   bsum   = (int*)(ws + 1600128);
  int*   csr    = (int*)(ws + 1600640);
  u16*   h1     = (u16*)(ws + 8000640);
  u16*   g      = (u16*)(ws + 33600640);
  u16*   h2     = (u16*)(ws + 8000640);      // overlay on h1

  hipMemsetAsync(ws, 0, 800000, stream);                     // cnt + cursor = 0

  k_count   <<<NE / 256, 256, 0, stream>>>(ei, cnt);
  k_dinv    <<<(NN + 255) / 256, 256, 0, stream>>>(cnt, dinv);
  k_blocksum<<<NB, 256, 0, stream>>>(cnt, bsum);
  k_scanbsum<<<1, 128, 0, stream>>>(bsum);
  k_scan3   <<<NB, 256, 0, stream>>>(cnt, bsum, offs);
  k_scatter <<<NE / 256, 256, 0, stream>>>(ei, offs, cursor, csr);

  k_gemm1   <<<(NN + 63) / 64, 256, 0, stream>>>(x, W1, h1);
  k_prop1   <<<NN, 128, 0, stream>>>(h1, dinv, offs, csr, b1, g);
  k_gemm2   <<<(NN + 7) / 8, 320, 0, stream>>>(g, W2, h2);
  k_prop2   <<<NN, 64, 0, stream>>>(h2, dinv, offs, csr, b2, out);
}

// Round 5
// 752.773 us; speedup vs baseline: 1.1769x; 1.1769x over previous
//
#include <hip/hip_runtime.h>
#include <hip/hip_bf16.h>

typedef unsigned short u16;
typedef __attribute__((ext_vector_type(8))) short short8;
typedef __attribute__((ext_vector_type(4))) float f32x4;

#define NN   100000
#define NE   1600000
#define DIN  512
#define DHID 128
#define DOUT 40
#define NB   98          // ceil(NN / 1024) scan blocks

__device__ __forceinline__ float bf2f(u16 u) {
  union { unsigned int i; float f; } v; v.i = ((unsigned int)u) << 16; return v.f;
}
__device__ __forceinline__ u16 f2bf(float f) {
  __hip_bfloat16 h = __float2bfloat16(f);
  return *reinterpret_cast<u16*>(&h);
}

// ---------------- graph build ----------------
// dtypes (HW-verified over rounds 1-4): ei int32, x/W1/b1/W2/b2 fp32, d_out fp32.

__global__ __launch_bounds__(256) void k_count(const int* __restrict__ ei, int* __restrict__ cnt) {
  int e = blockIdx.x * 256 + threadIdx.x;      // grid sized exactly NE/256
  int d = ei[NE + e];
  atomicAdd(&cnt[d], 1);
}

__global__ __launch_bounds__(256) void k_dinv(const int* __restrict__ cnt, float* __restrict__ dinv) {
  int i = blockIdx.x * 256 + threadIdx.x;
  if (i < NN) dinv[i] = rsqrtf((float)(cnt[i] + 1));   // +1 self-loop, always > 0
}

__global__ __launch_bounds__(256) void k_blocksum(const int* __restrict__ cnt, int* __restrict__ bsum) {
  __shared__ int s[256];
  int b = blockIdx.x, t = threadIdx.x;
  int base = b * 1024 + t * 4;
  int tot = 0;
  if (base < NN) { int4 v = *(const int4*)&cnt[base]; tot = v.x + v.y + v.z + v.w; }
  s[t] = tot; __syncthreads();
  for (int o = 128; o > 0; o >>= 1) { if (t < o) s[t] += s[t + o]; __syncthreads(); }
  if (t == 0) bsum[b] = s[0];
}

__global__ __launch_bounds__(128) void k_scanbsum(int* __restrict__ bsum) {
  __shared__ int s[128];
  int t = threadIdx.x;
  int v = (t < NB) ? bsum[t] : 0;
  s[t] = v; __syncthreads();
  for (int o = 1; o < 128; o <<= 1) {
    int add = (t >= o) ? s[t - o] : 0;
    __syncthreads();
    s[t] += add;
    __syncthreads();
  }
  if (t < NB) bsum[t] = s[t] - v;   // exclusive scan of block totals
}

__global__ __launch_bounds__(256) void k_scan3(const int* __restrict__ cnt, const int* __restrict__ bsum,
                                               int* __restrict__ offs) {
  __shared__ int s[256];
  int b = blockIdx.x, t = threadIdx.x;
  int base = b * 1024 + t * 4;
  int4 v = make_int4(0, 0, 0, 0);
  if (base < NN) v = *(const int4*)&cnt[base];
  int tot = v.x + v.y + v.z + v.w;
  s[t] = tot; __syncthreads();
  for (int o = 1; o < 256; o <<= 1) {
    int add = (t >= o) ? s[t - o] : 0;
    __syncthreads();
    s[t] += add;
    __syncthreads();
  }
  int tp = s[t] - tot;              // exclusive prefix of thread totals
  int b0 = bsum[b] + tp;
  if (base < NN) {
    int4 o4;
    o4.x = b0;
    o4.y = b0 + v.x;
    o4.z = b0 + v.x + v.y;
    o4.w = b0 + v.x + v.y + v.z;
    *(int4*)&offs[base] = o4;
  }
  if (b == 0 && t == 0) offs[NN] = NE;
}

__global__ __launch_bounds__(256) void k_scatter(const int* __restrict__ ei, const int* __restrict__ offs,
                                                 int* __restrict__ cursor, int* __restrict__ csr) {
  int e = blockIdx.x * 256 + threadIdx.x;
  int srcv = ei[e];
  int d = ei[NE + e];
  int pos = offs[d] + atomicAdd(&cursor[d], 1);
  csr[pos] = srcv;
}

// ---------------- W1 -> bf16, transposed: wt[n][k] = bf16(W1[k][n]) ----------------

__global__ __launch_bounds__(256) void k_prepw(const float* __restrict__ W1, u16* __restrict__ wt) {
  int id = blockIdx.x * 256 + threadIdx.x;     // 65536 = 128 * 512
  int k = id & 511, n = id >> 9;
  wt[n * DIN + k] = f2bf(W1[k * DHID + n]);
}

// ---------------- GEMM1 (MFMA): h1[NN][128] = x[NN][512] @ W1[512][128], bf16 out -------
// Block: 64 rows x 128 cols, 256 thr = 4 waves; wave w -> rows w*16..w*16+15, all 8 n-tiles.
// mfma_f32_16x16x32_bf16: A[m=lane&15][k=(lane>>4)*8+j], B[n=lane&15][k=(lane>>4)*8+j],
// C/D: col=lane&15, row=(lane>>4)*4+reg  (guide-verified m89/m91).

__global__ __launch_bounds__(256) void k_gemm1(const float* __restrict__ x, const u16* __restrict__ wt,
                                               u16* __restrict__ h1) {
  __shared__ u16 xs[64][72];        // 64 rows x 64-K bf16, row stride 144B   (9.2 KB)
  __shared__ u16 ws[128][72];       // 128 cols x 64-K bf16 (B^T layout)      (18.4 KB)
  int t = threadIdx.x;
  int row0 = blockIdx.x * 64;
  int w = t >> 6, l = t & 63;
  int lm = l & 15, lq = l >> 4;     // col-in-tile / quad
  int mbase = w * 16;
  f32x4 acc[8];
#pragma unroll
  for (int nt = 0; nt < 8; nt++) acc[nt] = (f32x4){0.f, 0.f, 0.f, 0.f};

  for (int c = 0; c < 8; c++) {
    int k0 = c * 64;
    // stage x tile: 64 rows x 64 K, fp32 -> bf16 (1024 float4 units)
#pragma unroll
    for (int it = 0; it < 4; it++) {
      int u = t + it * 256;
      int row = u >> 4, seg = u & 15;
      int gr = row0 + row;
      float4 v = make_float4(0.f, 0.f, 0.f, 0.f);
      if (gr < NN) v = *(const float4*)&x[gr * DIN + k0 + seg * 4];
      ushort4 o;
      o.x = f2bf(v.x); o.y = f2bf(v.y); o.z = f2bf(v.z); o.w = f2bf(v.w);
      *(ushort4*)&xs[row][seg * 4] = o;
    }
    // stage W^T tile: 128 cols x 64 K bf16 (1024 x 16B units, contiguous copies)
#pragma unroll
    for (int it = 0; it < 4; it++) {
      int u = t + it * 256;
      int n = u >> 3, seg = u & 7;
      *(uint4*)&ws[n][seg * 8] = *(const uint4*)&wt[n * DIN + k0 + seg * 8];
    }
    __syncthreads();
#pragma unroll
    for (int s = 0; s < 2; s++) {
      short8 a = *(const short8*)&xs[mbase + lm][s * 32 + lq * 8];
#pragma unroll
      for (int nt = 0; nt < 8; nt++) {
        short8 b = *(const short8*)&ws[nt * 16 + lm][s * 32 + lq * 8];
        acc[nt] = __builtin_amdgcn_mfma_f32_16x16x32_bf16(a, b, acc[nt], 0, 0, 0);
      }
    }
    __syncthreads();
  }
  // epilogue: lane holds (row = lq*4+reg, col = lm) of each 16x16 tile
#pragma unroll
  for (int reg = 0; reg < 4; reg++) {
    int gr = row0 + mbase + lq * 4 + reg;
    if (gr < NN) {
#pragma unroll
      for (int nt = 0; nt < 8; nt++) {
        h1[gr * DHID + nt * 16 + lm] = f2bf(acc[nt][reg]);
      }
    }
  }
}

// ---------------- prop1: g = relu(b1 + Ahat @ h1), bf16 intermediate ----------------

__global__ __launch_bounds__(128) void k_prop1(const u16* __restrict__ h1, const float* __restrict__ dinv,
                                               const int* __restrict__ offs, const int* __restrict__ csr,
                                               const float* __restrict__ b1, u16* __restrict__ g) {
  int n = blockIdx.x, f = threadIdx.x;
  float dn = dinv[n];
  float acc = b1[f] + dn * dn * bf2f(h1[n * DHID + f]);   // self-loop
  int p = offs[n], p1 = offs[n + 1];
  for (; p + 4 <= p1; p += 4) {
    int s0 = csr[p], s1 = csr[p + 1], s2 = csr[p + 2], s3 = csr[p + 3];
    float w0 = dinv[s0], w1 = dinv[s1], w2 = dinv[s2], w3 = dinv[s3];
    float v0 = bf2f(h1[s0 * DHID + f]);
    float v1 = bf2f(h1[s1 * DHID + f]);
    float v2 = bf2f(h1[s2 * DHID + f]);
    float v3 = bf2f(h1[s3 * DHID + f]);
    acc += dn * (w0 * v0 + w1 * v1 + w2 * v2 + w3 * v3);
  }
  for (; p < p1; p++) {
    int s0 = csr[p];
    acc += dn * dinv[s0] * bf2f(h1[s0 * DHID + f]);
  }
  g[n * DHID + f] = f2bf(fmaxf(acc, 0.f));
}

// ---------------- GEMM2: h2[NN][40] = g[NN][128] @ W2[128][40] ----------------

__global__ __launch_bounds__(320) void k_gemm2(const u16* __restrict__ g, const float* __restrict__ W2,
                                               u16* __restrict__ h2) {
  __shared__ float w2s[DHID][DOUT];   // 20 KB
  __shared__ float gs[8][DHID];       // 4 KB
  int t = threadIdx.x;
  int row0 = blockIdx.x * 8;
  for (int idx = t; idx < DHID * DOUT; idx += 320) ((float*)w2s)[idx] = W2[idx];
  for (int idx = t; idx < 8 * DHID; idx += 320) {
    int r = idx >> 7, k = idx & 127;
    int gr = row0 + r;
    ((float*)gs)[idx] = (gr < NN) ? bf2f(g[gr * DHID + k]) : 0.f;
  }
  __syncthreads();
  int r = t / DOUT, c = t % DOUT;     // 8 rows x 40 cols = 320 threads exactly
  float acc = 0.f;
#pragma unroll
  for (int k = 0; k < DHID; k += 4) {
    float4 gv = *(const float4*)&gs[r][k];
    acc += gv.x * w2s[k][c] + gv.y * w2s[k + 1][c] + gv.z * w2s[k + 2][c] + gv.w * w2s[k + 3][c];
  }
  int gr = row0 + r;
  if (gr < NN) h2[gr * DOUT + c] = f2bf(acc);
}

// ---------------- prop2 + log_softmax, fp32 out ----------------

__global__ __launch_bounds__(64) void k_prop2(const u16* __restrict__ h2, const float* __restrict__ dinv,
                                              const int* __restrict__ offs, const int* __restrict__ csr,
                                              const float* __restrict__ b2, float* __restrict__ out) {
  int n = blockIdx.x, c = threadIdx.x;
  bool act = c < DOUT;
  float dn = dinv[n];
  float acc = act ? (b2[c] + dn * dn * bf2f(h2[n * DOUT + c])) : 0.f;
  int p = offs[n], p1 = offs[n + 1];
  for (; p + 4 <= p1; p += 4) {
    int s0 = csr[p], s1 = csr[p + 1], s2 = csr[p + 2], s3 = csr[p + 3];
    float w0 = dinv[s0], w1 = dinv[s1], w2 = dinv[s2], w3 = dinv[s3];
    float v0 = act ? bf2f(h2[s0 * DOUT + c]) : 0.f;
    float v1 = act ? bf2f(h2[s1 * DOUT + c]) : 0.f;
    float v2 = act ? bf2f(h2[s2 * DOUT + c]) : 0.f;
    float v3 = act ? bf2f(h2[s3 * DOUT + c]) : 0.f;
    acc += dn * (w0 * v0 + w1 * v1 + w2 * v2 + w3 * v3);
  }
  for (; p < p1; p++) {
    int s0 = csr[p];
    float v0 = act ? bf2f(h2[s0 * DOUT + c]) : 0.f;
    acc += dn * dinv[s0] * v0;
  }
  float logit = act ? acc : -INFINITY;
  float mx = logit;
#pragma unroll
  for (int o = 32; o > 0; o >>= 1) mx = fmaxf(mx, __shfl_xor(mx, o));
  float pv = act ? __expf(logit - mx) : 0.f;
  float sm = pv;
#pragma unroll
  for (int o = 32; o > 0; o >>= 1) sm += __shfl_xor(sm, o);
  if (act) out[n * DOUT + c] = logit - mx - logf(sm);
}

// ---------------- launch ----------------

extern "C" void kernel_launch(void* const* d_in, const int* in_sizes, int n_in,
                              void* d_out, int out_size, void* d_ws, size_t ws_size,
                              hipStream_t stream) {
  const float* x  = (const float*)d_in[0];   // fp32
  const int* ei   = (const int*)d_in[1];     // int32 on device
  const float* W1 = (const float*)d_in[2];
  const float* b1 = (const float*)d_in[3];
  const float* W2 = (const float*)d_in[4];
  const float* b2 = (const float*)d_in[5];
  float* out      = (float*)d_out;           // fp32 output

  char* ws = (char*)d_ws;
  // layout (bytes): cnt 400000 | cursor 400000 | dinv 400000 | offs 400128 | bsum 512 | csr 6400000 |
  //                 h1 25600000 (h2 overlays h1) | g 25600000 | wt 131072 -> total ~59.34 MB
  int*   cnt    = (int*)(ws + 0);
  int*   cursor = (int*)(ws + 400000);
  float* dinv   = (float*)(ws + 800000);
  int*   offs   = (int*)(ws + 1200000);
  int*   bsum   = (int*)(ws + 1600128);
  int*   csr    = (int*)(ws + 1600640);
  u16*   h1     = (u16*)(ws + 8000640);
  u16*   g      = (u16*)(ws + 33600640);
  u16*   h2     = (u16*)(ws + 8000640);      // overlay on h1
  u16*   wt     = (u16*)(ws + 59200640);     // W1^T in bf16: [128][512]

  hipMemsetAsync(ws, 0, 800000, stream);                     // cnt + cursor = 0

  k_count   <<<NE / 256, 256, 0, stream>>>(ei, cnt);
  k_dinv    <<<(NN + 255) / 256, 256, 0, stream>>>(cnt, dinv);
  k_blocksum<<<NB, 256, 0, stream>>>(cnt, bsum);
  k_scanbsum<<<1, 128, 0, stream>>>(bsum);
  k_scan3   <<<NB, 256, 0, stream>>>(cnt, bsum, offs);
  k_scatter <<<NE / 256, 256, 0, stream>>>(ei, offs, cursor, csr);

  k_prepw   <<<(DIN * DHID) / 256, 256, 0, stream>>>(W1, wt);
  k_gemm1   <<<(NN + 63) / 64, 256, 0, stream>>>(x, wt, h1);
  k_prop1   <<<NN, 128, 0, stream>>>(h1, dinv, offs, csr, b1, g);
  k_gemm2   <<<(NN + 7) / 8, 320, 0, stream>>>(g, W2, h2);
  k_prop2   <<<NN, 64, 0, stream>>>(h2, dinv, offs, csr, b2, out);
}